// Round 1
// baseline (547.061 us; speedup 1.0000x reference)
//
#include <hip/hip_runtime.h>

typedef _Float16 half8 __attribute__((ext_vector_type(8)));
typedef float floatx4 __attribute__((ext_vector_type(4)));
typedef int intx4 __attribute__((ext_vector_type(4)));

#define MFMA16(a, b, c) __builtin_amdgcn_mfma_f32_16x16x32_f16(a, b, c, 0, 0, 0)

static constexpr int kC = 64, kH = 64, kW = 64;
static constexpr int kM = 512, kD = 576;  // D = C*9
// ws element offsets (f16 elements)
static constexpr int WS_MH = 0;            // mem_hi  [512][576]
static constexpr int WS_ML = 294912;       // mem_lo  [512][576]
static constexpr int WS_TH = 589824;       // memT_hi [576][512]
static constexpr int WS_TL = 884736;       // memT_lo [576][512]
// total ws need: 1179648 f16 = 2,359,296 bytes

// Split memory into f16 hi/lo, row-major (GEMM1 B) and transposed (GEMM2 B).
__global__ void prep_split(const float* __restrict__ mem, _Float16* __restrict__ ws) {
  const int m = blockIdx.x;   // 512
  const int d = threadIdx.x;  // 576
  float v = mem[m * kD + d];
  _Float16 hi = (_Float16)v;
  _Float16 lo = (_Float16)(v - (float)hi);
  ws[WS_MH + m * kD + d] = hi;
  ws[WS_ML + m * kD + d] = lo;
  ws[WS_TH + d * kM + m] = hi;
  ws[WS_TL + d * kM + m] = lo;
}

// One block: 32 pixels (b, h, w0..w0+31). 4 waves.
// GEMM1: sim[32][512] = patches @ memory^T (3-term f16 split, fp32 acc)
// softmax over 512 (exact, in log2 domain), GEMM2: out[32][576] = att @ memory.
__global__ __launch_bounds__(256, 2) void mem_branch_kernel(
    const float* __restrict__ x, const float* __restrict__ temperature,
    const _Float16* __restrict__ ws, float* __restrict__ out) {
  // A fragments: [36 combos (kt*2+rt)][64 lanes][8 f16]; hi at 0, lo at +18432.
  // Later aliased by att fragments: [32 combos (kt2*2+rt)][64][8]; hi 0, lo +16384.
  __shared__ __align__(16) _Float16 afrag[36 * 64 * 8 * 2];
  __shared__ __align__(16) int tab[kD];
  __shared__ float red_max[4][32];
  __shared__ float red_sum[4][32];

  const int tid = threadIdx.x;
  const int lane = tid & 63;
  const int wv = tid >> 6;
  const int l15 = lane & 15;
  const int koct = lane >> 4;  // 0..3
  const int bx = blockIdx.x;
  const int b = bx >> 7;
  const int h = (bx >> 1) & 63;
  const int w0 = (bx & 1) << 5;

  // d -> (c*4096 + kh*64 + kw) | kh<<20 | kw<<24
  for (int d = tid; d < kD; d += 256) {
    int c = d / 9, r9 = d % 9, kh = r9 / 3, kw = r9 % 3;
    tab[d] = (c << 12) + (kh << 6) + kw + (kh << 20) + (kw << 24);
  }
  __syncthreads();

  // ---- build patch A-fragments (hi/lo f16) directly in fragment layout ----
  {
    const int base0 = ((b * kC) * kH + (h - 1)) * kW + (w0 - 1);
    for (int combo = wv; combo < 36; combo += 4) {
      const int kt = combo >> 1, rt = combo & 1;
      const int pp = rt * 16 + l15;        // pixel 0..31
      const int dbase = kt * 32 + koct * 8;
      intx4 t0 = *reinterpret_cast<const intx4*>(&tab[dbase]);
      intx4 t1 = *reinterpret_cast<const intx4*>(&tab[dbase + 4]);
      half8 hv, lv;
#pragma unroll
      for (int j = 0; j < 8; ++j) {
        int t = (j < 4) ? t0[j] : t1[j - 4];
        int off = t & 0xFFFFF;
        int kh = (t >> 20) & 15;
        int kw = (t >> 24) & 15;
        bool ok = ((unsigned)(h - 1 + kh) < 64u) && ((unsigned)(w0 + pp - 1 + kw) < 64u);
        int idx = ok ? (base0 + pp + off) : 0;  // clamp to safe addr, mask value
        float v = x[idx];
        v = ok ? v : 0.0f;
        _Float16 hi = (_Float16)v;
        hv[j] = hi;
        lv[j] = (_Float16)(v - (float)hi);
      }
      *reinterpret_cast<half8*>(&afrag[(combo * 64 + lane) * 8]) = hv;
      *reinterpret_cast<half8*>(&afrag[18432 + (combo * 64 + lane) * 8]) = lv;
    }
  }
  __syncthreads();

  // ---- GEMM1: each wave owns m in [wv*128, wv*128+128), 8 m-tiles ----
  const float sfac = temperature[0] * 0.060112293370373475f;  // (1/24)*log2(e)
  floatx4 acc[2][8];
  const floatx4 zed = {0.0f, 0.0f, 0.0f, 0.0f};
#pragma unroll
  for (int rt = 0; rt < 2; ++rt)
#pragma unroll
    for (int mt = 0; mt < 8; ++mt) acc[rt][mt] = zed;
  {
    const _Float16* mh = ws + WS_MH;
    const _Float16* ml = ws + WS_ML;
    const int mrow = wv * 128 + l15;
    const int kc8 = koct * 8;
    for (int kt = 0; kt < 18; ++kt) {
      half8 ah0 = *reinterpret_cast<const half8*>(&afrag[((kt * 2 + 0) * 64 + lane) * 8]);
      half8 ah1 = *reinterpret_cast<const half8*>(&afrag[((kt * 2 + 1) * 64 + lane) * 8]);
      half8 al0 = *reinterpret_cast<const half8*>(&afrag[18432 + ((kt * 2 + 0) * 64 + lane) * 8]);
      half8 al1 = *reinterpret_cast<const half8*>(&afrag[18432 + ((kt * 2 + 1) * 64 + lane) * 8]);
      const int col = kt * 32 + kc8;
#pragma unroll
      for (int mt = 0; mt < 8; ++mt) {
        const int m = mrow + mt * 16;
        half8 bh = *reinterpret_cast<const half8*>(&mh[m * kD + col]);
        half8 bl = *reinterpret_cast<const half8*>(&ml[m * kD + col]);
        acc[0][mt] = MFMA16(ah0, bh, acc[0][mt]);
        acc[1][mt] = MFMA16(ah1, bh, acc[1][mt]);
        acc[0][mt] = MFMA16(ah0, bl, acc[0][mt]);
        acc[1][mt] = MFMA16(ah1, bl, acc[1][mt]);
        acc[0][mt] = MFMA16(al0, bh, acc[0][mt]);
        acc[1][mt] = MFMA16(al1, bh, acc[1][mt]);
      }
    }
  }
#pragma unroll
  for (int rt = 0; rt < 2; ++rt)
#pragma unroll
    for (int mt = 0; mt < 8; ++mt) acc[rt][mt] *= sfac;

  // ---- softmax over m (512) ----
  // lane holds sim[p][m]: p = rt*16 + koct*4 + r, m = wv*128 + mt*16 + l15
  float pm[2][4], ps[2][4], gm[2][4], rinv[2][4];
#pragma unroll
  for (int rt = 0; rt < 2; ++rt)
#pragma unroll
    for (int r = 0; r < 4; ++r) {
      float v = acc[rt][0][r];
#pragma unroll
      for (int mt = 1; mt < 8; ++mt) v = fmaxf(v, acc[rt][mt][r]);
      pm[rt][r] = v;
    }
#pragma unroll
  for (int off = 1; off < 16; off <<= 1)
#pragma unroll
    for (int rt = 0; rt < 2; ++rt)
#pragma unroll
      for (int r = 0; r < 4; ++r) pm[rt][r] = fmaxf(pm[rt][r], __shfl_xor(pm[rt][r], off, 64));
  if (l15 == 0) {
#pragma unroll
    for (int rt = 0; rt < 2; ++rt)
#pragma unroll
      for (int r = 0; r < 4; ++r) red_max[wv][rt * 16 + koct * 4 + r] = pm[rt][r];
  }
  __syncthreads();
#pragma unroll
  for (int rt = 0; rt < 2; ++rt)
#pragma unroll
    for (int r = 0; r < 4; ++r) {
      int p = rt * 16 + koct * 4 + r;
      gm[rt][r] = fmaxf(fmaxf(red_max[0][p], red_max[1][p]), fmaxf(red_max[2][p], red_max[3][p]));
      ps[rt][r] = 0.0f;
    }
#pragma unroll
  for (int rt = 0; rt < 2; ++rt)
#pragma unroll
    for (int mt = 0; mt < 8; ++mt)
#pragma unroll
      for (int r = 0; r < 4; ++r) {
        float e = exp2f(acc[rt][mt][r] - gm[rt][r]);
        acc[rt][mt][r] = e;
        ps[rt][r] += e;
      }
#pragma unroll
  for (int off = 1; off < 16; off <<= 1)
#pragma unroll
    for (int rt = 0; rt < 2; ++rt)
#pragma unroll
      for (int r = 0; r < 4; ++r) ps[rt][r] += __shfl_xor(ps[rt][r], off, 64);
  if (l15 == 0) {
#pragma unroll
    for (int rt = 0; rt < 2; ++rt)
#pragma unroll
      for (int r = 0; r < 4; ++r) red_sum[wv][rt * 16 + koct * 4 + r] = ps[rt][r];
  }
  __syncthreads();
#pragma unroll
  for (int rt = 0; rt < 2; ++rt)
#pragma unroll
    for (int r = 0; r < 4; ++r) {
      int p = rt * 16 + koct * 4 + r;
      rinv[rt][r] = 1.0f / (red_sum[0][p] + red_sum[1][p] + red_sum[2][p] + red_sum[3][p]);
    }
  // write att hi/lo fragments into (aliased) afrag; safe: 2 syncs since last A read
#pragma unroll
  for (int rt = 0; rt < 2; ++rt)
#pragma unroll
    for (int mt = 0; mt < 8; ++mt)
#pragma unroll
      for (int r = 0; r < 4; ++r) {
        float a = acc[rt][mt][r] * rinv[rt][r];
        _Float16 hi = (_Float16)a;
        _Float16 lo = (_Float16)(a - (float)hi);
        int m = wv * 128 + mt * 16 + l15;
        int lf = (koct * 4 + r) + (((m >> 3) & 3) << 4);
        int idxe = ((((m >> 5) << 1) + rt) * 64 + lf) * 8 + (m & 7);
        afrag[idxe] = hi;
        afrag[16384 + idxe] = lo;
      }
  __syncthreads();

  // ---- GEMM2: out[32][576] = att @ memory; wave owns d in [wv*144, wv*144+144) ----
  floatx4 acc2[2][9];
#pragma unroll
  for (int rt = 0; rt < 2; ++rt)
#pragma unroll
    for (int nt = 0; nt < 9; ++nt) acc2[rt][nt] = zed;
  {
    const _Float16* th = ws + WS_TH;
    const _Float16* tl = ws + WS_TL;
    const int d0 = wv * 144 + l15;
    const int kc8 = koct * 8;
    for (int kt2 = 0; kt2 < 16; ++kt2) {
      half8 a2h0 = *reinterpret_cast<const half8*>(&afrag[((kt2 * 2 + 0) * 64 + lane) * 8]);
      half8 a2h1 = *reinterpret_cast<const half8*>(&afrag[((kt2 * 2 + 1) * 64 + lane) * 8]);
      half8 a2l0 = *reinterpret_cast<const half8*>(&afrag[16384 + ((kt2 * 2 + 0) * 64 + lane) * 8]);
      half8 a2l1 = *reinterpret_cast<const half8*>(&afrag[16384 + ((kt2 * 2 + 1) * 64 + lane) * 8]);
      const int kcol = kt2 * 32 + kc8;
#pragma unroll
      for (int nt = 0; nt < 9; ++nt) {
        const int d = d0 + nt * 16;
        half8 bh = *reinterpret_cast<const half8*>(&th[d * kM + kcol]);
        half8 bl = *reinterpret_cast<const half8*>(&tl[d * kM + kcol]);
        acc2[0][nt] = MFMA16(a2h0, bh, acc2[0][nt]);
        acc2[1][nt] = MFMA16(a2h1, bh, acc2[1][nt]);
        acc2[0][nt] = MFMA16(a2h0, bl, acc2[0][nt]);
        acc2[1][nt] = MFMA16(a2h1, bl, acc2[1][nt]);
        acc2[0][nt] = MFMA16(a2l0, bh, acc2[0][nt]);
        acc2[1][nt] = MFMA16(a2l1, bh, acc2[1][nt]);
      }
    }
  }
  // ---- epilogue ----
  {
    const int nbase = b * 4096 + h * 64 + w0;
#pragma unroll
    for (int rt = 0; rt < 2; ++rt)
#pragma unroll
      for (int nt = 0; nt < 9; ++nt)
#pragma unroll
        for (int r = 0; r < 4; ++r) {
          int p = rt * 16 + koct * 4 + r;
          int d = wv * 144 + l15 + nt * 16;
          out[(nbase + p) * 576 + d] = acc2[rt][nt][r];
        }
  }
}

extern "C" void kernel_launch(void* const* d_in, const int* in_sizes, int n_in,
                              void* d_out, int out_size, void* d_ws, size_t ws_size,
                              hipStream_t stream) {
  const float* x = (const float*)d_in[0];
  const float* memory = (const float*)d_in[1];
  const float* temperature = (const float*)d_in[2];
  float* out = (float*)d_out;
  _Float16* ws = (_Float16*)d_ws;  // needs 2,359,296 bytes

  prep_split<<<512, 576, 0, stream>>>(memory, ws);
  mem_branch_kernel<<<2048, 256, 0, stream>>>(x, temperature, ws, out);
}